// Round 3
// baseline (212.846 us; speedup 1.0000x reference)
//
#include <hip/hip_runtime.h>

// Attention: B=8, N=4096, D=64, fp32 in/out, causal + padding mask.
// Flash-attention, bf16 MFMA (16x16x32), S^T orientation, online softmax.
// R3: q-tile 32, intra-block split-K (waves 0,1 = even k-tiles, waves 2,3 =
//     odd k-tiles, flash-combine at end) -> grid 1024, chain halved, 3
//     blocks/CU. V and P stored with permuted key order kidx=(key&15)*4+
//     (key>>4) so all staging writes are ds_write_b64 at <=2-way conflict.

#define BATCH 8
#define SEQ   4096
#define DIM   64
#define QT    32

typedef __attribute__((ext_vector_type(8))) short bf16x8;
typedef __attribute__((ext_vector_type(4))) float f32x4;

__device__ inline short f2bf(float f) {
    unsigned u = __builtin_bit_cast(unsigned, f);
    u += 0x7FFFu + ((u >> 16) & 1u);   // RNE
    return (short)(u >> 16);
}

__device__ inline float fast_exp2(float x) {
#if __has_builtin(__builtin_amdgcn_exp2f)
    return __builtin_amdgcn_exp2f(x);
#else
    return exp2f(x);
#endif
}

__global__ __launch_bounds__(256, 3)
void attn_fwd(const float* __restrict__ qg, const float* __restrict__ kg,
              const float* __restrict__ vg, const int* __restrict__ mg,
              float* __restrict__ og) {
    // LDS layout (44768 B total):
    //  Klds: 2 tiles x 519*8 shorts (cell (d>>3)*65+key, 8 d's per cell)
    //  Vlds: 2 tiles x 64*72 shorts (row d, 64 kidx + 8 pad)
    //  Plds: 4 waves x 16*72 shorts (row q, 64 kidx + 8 pad)
    //  Mlds: 2 tiles x 64 floats
    __shared__ __align__(16) char smem[44768];
    short* Klds = (short*)smem;             // 16608 B
    short* Vlds = (short*)(smem + 16608);   // 18432 B
    short* Plds = (short*)(smem + 35040);   //  9216 B
    float* Mlds = (float*)(smem + 44256);   //   512 B
    // combine region aliases Klds (used only after final barrier)
    float* OX = (float*)smem;               // [32][64] fp32 = 8192 B
    float* MX = (float*)(smem + 8192);      // [32]
    float* LX = (float*)(smem + 8320);      // [32]

    const int t    = threadIdx.x;
    const int w    = t >> 6;       // wave 0..3
    const int L    = t & 63;
    const int c15  = L & 15;
    const int quad = L >> 4;
    const int half = w >> 1;       // 0: even k-tiles, 1: odd k-tiles
    const int qh   = w & 1;        // q sub-block (rows qh*16..qh*16+15)
    const int b    = blockIdx.y;
    const int qt   = (int)gridDim.x - 1 - (int)blockIdx.x; // big blocks first
    const int qbase = qt * QT;
    const int ntiles = (qt >> 1) + 1;        // k-tiles of 64 needed (causal)
    const int nss    = (ntiles + 1) >> 1;    // supersteps (2 tiles each)

    const float* qp = qg + (size_t)b * SEQ * DIM;
    const float* kp = kg + (size_t)b * SEQ * DIM;
    const float* vp = vg + (size_t)b * SEQ * DIM;
    const int*   mp = mg + (size_t)b * SEQ;

    const int qrow = qbase + qh * 16 + c15;  // this lane's q column (S^T)
    const float qscale = 0.125f * 1.44269504088896340736f; // 1/sqrt(64)*log2e

    // Q B-fragments, scale folded in. n=lane&15(=q), k=quad*8+j (+32c)
    bf16x8 Qf[2];
#pragma unroll
    for (int c = 0; c < 2; ++c) {
        const float* src = qp + (size_t)qrow * DIM + c * 32 + quad * 8;
        float4 x = *(const float4*)(src);
        float4 y = *(const float4*)(src + 4);
        bf16x8 f;
        f[0] = f2bf(x.x * qscale); f[1] = f2bf(x.y * qscale);
        f[2] = f2bf(x.z * qscale); f[3] = f2bf(x.w * qscale);
        f[4] = f2bf(y.x * qscale); f[5] = f2bf(y.y * qscale);
        f[6] = f2bf(y.z * qscale); f[7] = f2bf(y.w * qscale);
        Qf[c] = f;
    }

    // staging coords: thread covers, per tile-local tl=i>>2, key=(i&3)*16+h
    const int h  = t >> 4;          // 0..15 (key group)
    const int d0 = (t & 15) * 4;    // 0..60

    float4 kreg[8], vreg[8];
    int mreg = 1;

    auto loadpair = [&](int p) {    // global -> regs for pair p (tiles 2p,2p+1)
#pragma unroll
        for (int i = 0; i < 8; ++i) {
            const size_t row = (size_t)((2 * p + (i >> 2)) * 64 + (i & 3) * 16 + h);
            kreg[i] = *(const float4*)(kp + row * DIM + d0);
            vreg[i] = *(const float4*)(vp + row * DIM + d0);
        }
        if (t < 128) mreg = mp[(2 * p + (t >> 6)) * 64 + (t & 63)];
    };

    auto writebuf = [&]() {         // regs -> LDS (both tiles of the pair)
#pragma unroll
        for (int i = 0; i < 8; ++i) {
            const int tl = i >> 2, key = (i & 3) * 16 + h;
            short4 ks;
            ks.x = f2bf(kreg[i].x); ks.y = f2bf(kreg[i].y);
            ks.z = f2bf(kreg[i].z); ks.w = f2bf(kreg[i].w);
            *(short4*)&Klds[tl * 4152 + ((d0 >> 3) * 65 + key) * 8 + (d0 & 7)] = ks;
        }
        // V: thread holds 4 keys x 4 d per tile; write along kidx=4h+i_loc
#pragma unroll
        for (int tl = 0; tl < 2; ++tl) {
            const float* vr = (const float*)&vreg[tl * 4];
#pragma unroll
            for (int dd = 0; dd < 4; ++dd) {
                short4 vs;
                vs.x = f2bf(vr[0 * 4 + dd]); vs.y = f2bf(vr[1 * 4 + dd]);
                vs.z = f2bf(vr[2 * 4 + dd]); vs.w = f2bf(vr[3 * 4 + dd]);
                *(short4*)&Vlds[tl * 4608 + (d0 + dd) * 72 + 4 * h] = vs;
            }
        }
        if (t < 128) Mlds[(t >> 6) * 64 + (t & 63)] = mreg ? 0.0f : -1e30f;
    };

    float mrun = -1e30f, lrun = 0.0f;
    f32x4 Oacc[4];
#pragma unroll
    for (int nb = 0; nb < 4; ++nb) Oacc[nb] = (f32x4){0.f, 0.f, 0.f, 0.f};

    // prologue: stage pair 0, prefetch pair 1
    loadpair(0);
    writebuf();
    if (1 < nss) loadpair(1);
    __syncthreads();

    const short* Kt = Klds + half * 4152;
    const short* Vt = Vlds + half * 4608;
    const float* Mt = Mlds + half * 64;
    short*       Pw = Plds + w * 1152;

    for (int ss = 0; ss < nss; ++ss) {
        const int tw = 2 * ss + half;      // my wave-group's k-tile
        if (tw < ntiles) {
            // ---- S^T = K @ Q^T
            f32x4 sacc[4];
#pragma unroll
            for (int kb = 0; kb < 4; ++kb) sacc[kb] = (f32x4){0.f, 0.f, 0.f, 0.f};
#pragma unroll
            for (int c = 0; c < 2; ++c) {
#pragma unroll
                for (int kb = 0; kb < 4; ++kb) {
                    bf16x8 kf = *(const bf16x8*)&Kt[((quad + 4 * c) * 65 + kb * 16 + c15) * 8];
                    sacc[kb] = __builtin_amdgcn_mfma_f32_16x16x32_bf16(kf, Qf[c], sacc[kb], 0, 0, 0);
                }
            }
            // ---- masks + online softmax (keys natural order here)
            float sv[4][4];
            float tmax = -1e30f;
            const bool diag = (tw == ntiles - 1);
#pragma unroll
            for (int kb = 0; kb < 4; ++kb) {
                float4 ma = *(const float4*)&Mt[kb * 16 + quad * 4];
                float mar[4] = {ma.x, ma.y, ma.z, ma.w};
#pragma unroll
                for (int r = 0; r < 4; ++r) {
                    float s = sacc[kb][r] + mar[r];
                    if (diag) {
                        int keyg = tw * 64 + kb * 16 + quad * 4 + r;
                        if (keyg > qrow) s = -1e30f;
                    }
                    sv[kb][r] = s;
                    tmax = fmaxf(tmax, s);
                }
            }
            tmax = fmaxf(tmax, __shfl_xor(tmax, 16));
            tmax = fmaxf(tmax, __shfl_xor(tmax, 32));
            float mnew  = fmaxf(mrun, tmax);
            float alpha = fast_exp2(mrun - mnew);
            mrun = mnew;

            float pexp[4][4];
            float tsum = 0.f;
#pragma unroll
            for (int kb = 0; kb < 4; ++kb) {
#pragma unroll
                for (int r = 0; r < 4; ++r) {
                    pexp[kb][r] = fast_exp2(sv[kb][r] - mnew);
                    tsum += pexp[kb][r];
                }
            }
            // P write in kidx order: keys {kb*16+quad*4+r} -> kidx=16quad+4r+kb
#pragma unroll
            for (int r = 0; r < 4; ++r) {
                short4 pb;
                pb.x = f2bf(pexp[0][r]); pb.y = f2bf(pexp[1][r]);
                pb.z = f2bf(pexp[2][r]); pb.w = f2bf(pexp[3][r]);
                *(short4*)&Pw[c15 * 72 + 16 * quad + 4 * r] = pb;
            }
            tsum += __shfl_xor(tsum, 16);
            tsum += __shfl_xor(tsum, 32);
            lrun = lrun * alpha + tsum;

            // alpha for this lane's O rows (q = quad*4+r)
            float ar[4];
#pragma unroll
            for (int r = 0; r < 4; ++r)
                ar[r] = __shfl(alpha, (L & 48) + ((L & 48) >> 2) + r);
#pragma unroll
            for (int nb = 0; nb < 4; ++nb) {
#pragma unroll
                for (int r = 0; r < 4; ++r) Oacc[nb][r] *= ar[r];
            }
            // ---- O += P @ V (both in kidx order -> contraction unchanged)
#pragma unroll
            for (int c = 0; c < 2; ++c) {
                bf16x8 pf = *(const bf16x8*)&Pw[c15 * 72 + quad * 8 + 32 * c];
#pragma unroll
                for (int nb = 0; nb < 4; ++nb) {
                    bf16x8 vf = *(const bf16x8*)&Vt[(nb * 16 + c15) * 72 + quad * 8 + 32 * c];
                    Oacc[nb] = __builtin_amdgcn_mfma_f32_16x16x32_bf16(pf, vf, Oacc[nb], 0, 0, 0);
                }
            }
        }
        __syncthreads();               // all reads of this pair done
        if (ss + 1 < nss) writebuf();  // stage next pair (regs already loaded)
        if (ss + 2 < nss) loadpair(ss + 2);
        __syncthreads();               // staged pair visible
    }

    // ---- combine the two k-streams (flash merge), then write output
    if (half == 1) {
#pragma unroll
        for (int r = 0; r < 4; ++r) {
            const int row = qh * 16 + quad * 4 + r;
#pragma unroll
            for (int nb = 0; nb < 4; ++nb)
                OX[row * 64 + nb * 16 + c15] = Oacc[nb][r];
        }
        if (quad == 0) { MX[qh * 16 + c15] = mrun; LX[qh * 16 + c15] = lrun; }
    }
    __syncthreads();
    if (half == 0) {
        float* op = og + (size_t)b * SEQ * DIM;
#pragma unroll
        for (int r = 0; r < 4; ++r) {
            const int q = quad * 4 + r;
            const int row16 = qh * 16 + q;
            float mA = __shfl(mrun, q);
            float lA = __shfl(lrun, q);
            float mB = MX[row16];
            float lB = LX[row16];
            float m  = fmaxf(mA, mB);
            float fa = fast_exp2(mA - m);
            float fb = fast_exp2(mB - m);
            float inv = 1.0f / (lA * fa + lB * fb);
            const size_t grow = (size_t)(qbase + row16);
#pragma unroll
            for (int nb = 0; nb < 4; ++nb) {
                float val = (Oacc[nb][r] * fa + OX[row16 * 64 + nb * 16 + c15] * fb) * inv;
                op[grow * DIM + nb * 16 + c15] = val;
            }
        }
    }
}

extern "C" void kernel_launch(void* const* d_in, const int* in_sizes, int n_in,
                              void* d_out, int out_size, void* d_ws, size_t ws_size,
                              hipStream_t stream) {
    (void)in_sizes; (void)n_in; (void)d_ws; (void)ws_size; (void)out_size;
    const float* q = (const float*)d_in[0];
    const float* k = (const float*)d_in[1];
    const float* v = (const float*)d_in[2];
    const int*   m = (const int*)d_in[3];
    float* o = (float*)d_out;
    dim3 grid(SEQ / QT, BATCH);
    attn_fwd<<<grid, 256, 0, stream>>>(q, k, v, m, o);
}

// Round 4
// 166.198 us; speedup vs baseline: 1.2807x; 1.2807x over previous
//
#include <hip/hip_runtime.h>

// Attention: B=8, N=4096, D=64, fp32 in/out, causal + padding mask.
// R4: pre-pass converts K,V -> bf16 tiles in d_ws (LDS-ready layouts);
//     main kernel stages via async global_load_lds dwordx4 (no VALU, no
//     VGPR round-trip), QT=64, double-buffered, 1 barrier/k-tile.

#define BATCH 8
#define SEQ   4096
#define DIM   64
#define QT    64
#define NKT   (SEQ / 64)

typedef __attribute__((ext_vector_type(8))) short bf16x8;
typedef __attribute__((ext_vector_type(4))) float f32x4;

__device__ inline short f2bf(float f) {
    unsigned u = __builtin_bit_cast(unsigned, f);
    u += 0x7FFFu + ((u >> 16) & 1u);   // RNE
    return (short)(u >> 16);
}

// pack bf16(a) | bf16(b)<<16 with round-half-up bias (1 add each + 1 perm)
__device__ inline unsigned pk2bf(float a, float b) {
    unsigned ua = __builtin_bit_cast(unsigned, a) + 0x8000u;
    unsigned ub = __builtin_bit_cast(unsigned, b) + 0x8000u;
    return __builtin_amdgcn_perm(ub, ua, 0x07060302u);
}

__device__ inline float fast_exp2(float x) {
#if __has_builtin(__builtin_amdgcn_exp2f)
    return __builtin_amdgcn_exp2f(x);
#else
    return exp2f(x);
#endif
}

__device__ inline void gl_lds16(const void* g, void* l) {
    __builtin_amdgcn_global_load_lds(
        (const __attribute__((address_space(1))) void*)g,
        (__attribute__((address_space(3))) void*)l, 16, 0, 0);
}
__device__ inline void gl_lds4(const void* g, void* l) {
    __builtin_amdgcn_global_load_lds(
        (const __attribute__((address_space(1))) void*)g,
        (__attribute__((address_space(3))) void*)l, 4, 0, 0);
}

// ---- pre-pass: fp32 K,V -> bf16 tiles, LDS-ready layouts ----
// K tile: cell(dchunk 0..7, key 0..63) = dchunk*64+key, 8 shorts (d within chunk)
// V tile: cell(kchunk 0..7, d 0..63)  = kchunk*64+d,   8 shorts (key within chunk)
__global__ __launch_bounds__(256)
void prep_kv(const float* __restrict__ kg, const float* __restrict__ vg,
             short* __restrict__ kw, short* __restrict__ vw) {
    const int tile = blockIdx.x;            // b*NKT + kt
    const float* kp = kg + (size_t)tile * 64 * DIM;
    const float* vp = vg + (size_t)tile * 64 * DIM;
    short* ko = kw + (size_t)tile * 4096;
    short* vo = vw + (size_t)tile * 4096;
    const int t = threadIdx.x;
#pragma unroll
    for (int i = 0; i < 4; ++i) {
        const int flat = i * 256 + t;
        const int key = flat >> 4, d0 = (flat & 15) * 4;
        const float4 kv = *(const float4*)(kp + (size_t)key * DIM + d0);
        uint2 kpk;
        kpk.x = pk2bf(kv.x, kv.y); kpk.y = pk2bf(kv.z, kv.w);
        *(uint2*)(ko + (((d0 >> 3) << 6) + key) * 8 + (d0 & 7)) = kpk;
        const float4 vv = *(const float4*)(vp + (size_t)key * DIM + d0);
        const int kc = key >> 3, jk = key & 7;
        vo[((kc << 6) + d0 + 0) * 8 + jk] = f2bf(vv.x);
        vo[((kc << 6) + d0 + 1) * 8 + jk] = f2bf(vv.y);
        vo[((kc << 6) + d0 + 2) * 8 + jk] = f2bf(vv.z);
        vo[((kc << 6) + d0 + 3) * 8 + jk] = f2bf(vv.w);
    }
}

template <bool WS>
__global__ __launch_bounds__(256, 2)
void attn_fwd(const float* __restrict__ qg, const float* __restrict__ kg,
              const float* __restrict__ vg, const int* __restrict__ mg,
              float* __restrict__ og, const short* __restrict__ kw,
              const short* __restrict__ vw) {
    __shared__ __align__(16) short Kb[2][4096];
    __shared__ __align__(16) short Vb[2][4096];
    __shared__ __align__(16) short Pb[4][1024];  // per wave: [kchunk 0..7][q 0..15][8]
    __shared__ int Mb[2][64];

    const int t    = threadIdx.x;
    const int w    = t >> 6;
    const int L    = t & 63;
    const int c15  = L & 15;
    const int quad = L >> 4;
    const int b    = blockIdx.y;
    const int qb   = (int)gridDim.x - 1 - (int)blockIdx.x; // big blocks first
    const int qbase = qb * QT;
    const int ntiles = qb + 1;

    const float* qp = qg + (size_t)b * SEQ * DIM;
    const float* kp = kg + (size_t)b * SEQ * DIM;
    const float* vp = vg + (size_t)b * SEQ * DIM;
    const int*   mp = mg + (size_t)b * SEQ;
    const short* kwb = WS ? kw + (size_t)b * NKT * 4096 : nullptr;
    const short* vwb = WS ? vw + (size_t)b * NKT * 4096 : nullptr;

    const int qrow = qbase + w * 16 + c15;   // lane's q column (S^T orientation)
    const float qscale = 0.125f * 1.44269504088896340736f; // 1/sqrt(64)*log2e

    // Q B-fragments, scale folded. n=lane&15(=q), k=quad*8+j (+32c)
    bf16x8 Qf[2];
#pragma unroll
    for (int c = 0; c < 2; ++c) {
        const float* src = qp + (size_t)qrow * DIM + c * 32 + quad * 8;
        float4 x = *(const float4*)(src);
        float4 y = *(const float4*)(src + 4);
        bf16x8 f;
        f[0] = f2bf(x.x * qscale); f[1] = f2bf(x.y * qscale);
        f[2] = f2bf(x.z * qscale); f[3] = f2bf(x.w * qscale);
        f[4] = f2bf(y.x * qscale); f[5] = f2bf(y.y * qscale);
        f[6] = f2bf(y.z * qscale); f[7] = f2bf(y.w * qscale);
        Qf[c] = f;
    }

    // async stage of tile kt into buffer bs (WS path only)
    auto stage = [&](int bs, int kt) {
        const short* ks = kwb + (size_t)kt * 4096;
        const short* vs = vwb + (size_t)kt * 4096;
#pragma unroll
        for (int it = 0; it < 2; ++it) {
            const int off = w * 1024 + it * 512;   // shorts; lane adds 8 shorts
            gl_lds16(ks + off + L * 8, &Kb[bs][off]);
            gl_lds16(vs + off + L * 8, &Vb[bs][off]);
        }
        if (w == 0) gl_lds4(mp + kt * 64 + L, &Mb[bs][0]);
    };

    float mrun = -1e30f, lrun = 0.0f;
    f32x4 Oacc[4];
#pragma unroll
    for (int nb = 0; nb < 4; ++nb) Oacc[nb] = (f32x4){0.f, 0.f, 0.f, 0.f};

    if constexpr (WS) stage(0, 0);

    for (int kt = 0; kt < ntiles; ++kt) {
        const int cur = WS ? (kt & 1) : 0;

        if constexpr (!WS) {
            float4 kr[4], vr[4];
            int mr = 1;
#pragma unroll
            for (int i = 0; i < 4; ++i) {
                const int flat = i * 256 + t;
                const int key = flat >> 4, d0 = (flat & 15) * 4;
                kr[i] = *(const float4*)(kp + (size_t)(kt * 64 + key) * DIM + d0);
                vr[i] = *(const float4*)(vp + (size_t)(kt * 64 + key) * DIM + d0);
            }
            if (t < 64) mr = mp[kt * 64 + t];
            __syncthreads();
#pragma unroll
            for (int i = 0; i < 4; ++i) {
                const int flat = i * 256 + t;
                const int key = flat >> 4, d0 = (flat & 15) * 4;
                uint2 kk;
                kk.x = pk2bf(kr[i].x, kr[i].y); kk.y = pk2bf(kr[i].z, kr[i].w);
                *(uint2*)&Kb[0][(((d0 >> 3) << 6) + key) * 8 + (d0 & 7)] = kk;
                const int kc = key >> 3, jk = key & 7;
                Vb[0][((kc << 6) + d0 + 0) * 8 + jk] = f2bf(vr[i].x);
                Vb[0][((kc << 6) + d0 + 1) * 8 + jk] = f2bf(vr[i].y);
                Vb[0][((kc << 6) + d0 + 2) * 8 + jk] = f2bf(vr[i].z);
                Vb[0][((kc << 6) + d0 + 3) * 8 + jk] = f2bf(vr[i].w);
            }
            if (t < 64) Mb[0][t] = mr;
            __syncthreads();
        } else {
            __syncthreads();   // buffer cur fully landed (vmcnt drained), prev reads done
            if (kt + 1 < ntiles) stage(cur ^ 1, kt + 1);
        }

        // ---- S^T = K @ Q^T : rows = keys (kb*16+quad*4+r), col = q (=c15)
        f32x4 sacc[4];
#pragma unroll
        for (int kb = 0; kb < 4; ++kb) sacc[kb] = (f32x4){0.f, 0.f, 0.f, 0.f};
#pragma unroll
        for (int c = 0; c < 2; ++c) {
#pragma unroll
            for (int kb = 0; kb < 4; ++kb) {
                bf16x8 kf = *(const bf16x8*)&Kb[cur][(((quad + 4 * c) << 6) + kb * 16 + c15) * 8];
                sacc[kb] = __builtin_amdgcn_mfma_f32_16x16x32_bf16(kf, Qf[c], sacc[kb], 0, 0, 0);
            }
        }

        // ---- masks + online softmax
        float sv[4][4];
        float tmax = -1e30f;
        const bool diag = (kt == ntiles - 1);
#pragma unroll
        for (int kb = 0; kb < 4; ++kb) {
            const int4 mm = *(const int4*)&Mb[cur][kb * 16 + quad * 4];
            const int mi[4] = {mm.x, mm.y, mm.z, mm.w};
#pragma unroll
            for (int r = 0; r < 4; ++r) {
                float s = sacc[kb][r] + (mi[r] ? 0.0f : -1e30f);
                if (diag) {
                    const int keyg = kt * 64 + kb * 16 + quad * 4 + r;
                    if (keyg > qrow) s = -1e30f;
                }
                sv[kb][r] = s;
                tmax = fmaxf(tmax, s);
            }
        }
        tmax = fmaxf(tmax, __shfl_xor(tmax, 16));
        tmax = fmaxf(tmax, __shfl_xor(tmax, 32));
        const float mnew  = fmaxf(mrun, tmax);
        const float alpha = fast_exp2(mrun - mnew);
        mrun = mnew;

        float pexp[4][4];
        float tsum = 0.f;
#pragma unroll
        for (int kb = 0; kb < 4; ++kb) {
#pragma unroll
            for (int r = 0; r < 4; ++r) {
                pexp[kb][r] = fast_exp2(sv[kb][r] - mnew);
                tsum += pexp[kb][r];
            }
        }
        // P write: keys kb*16+quad*4+r -> cell(kchunk=2kb+(quad>>1), q=c15), j=(quad&1)*4+r
#pragma unroll
        for (int kb = 0; kb < 4; ++kb) {
            uint2 pp;
            pp.x = pk2bf(pexp[kb][0], pexp[kb][1]);
            pp.y = pk2bf(pexp[kb][2], pexp[kb][3]);
            *(uint2*)&Pb[w][((2 * kb + (quad >> 1)) * 16 + c15) * 8 + (quad & 1) * 4] = pp;
        }
        tsum += __shfl_xor(tsum, 16);
        tsum += __shfl_xor(tsum, 32);
        lrun = lrun * alpha + tsum;

        // alpha for this lane's O rows (q = quad*4+r)
        float ar[4];
#pragma unroll
        for (int r = 0; r < 4; ++r)
            ar[r] = __shfl(alpha, (L & 48) + ((L & 48) >> 2) + r);
#pragma unroll
        for (int nb = 0; nb < 4; ++nb) {
#pragma unroll
            for (int r = 0; r < 4; ++r) Oacc[nb][r] *= ar[r];
        }

        // ---- O += P @ V
#pragma unroll
        for (int c = 0; c < 2; ++c) {
            bf16x8 pf = *(const bf16x8*)&Pb[w][((quad + 4 * c) * 16 + c15) * 8];
#pragma unroll
            for (int nb = 0; nb < 4; ++nb) {
                bf16x8 vf = *(const bf16x8*)&Vb[cur][(((quad + 4 * c) << 6) + nb * 16 + c15) * 8];
                Oacc[nb] = __builtin_amdgcn_mfma_f32_16x16x32_bf16(pf, vf, Oacc[nb], 0, 0, 0);
            }
        }
    }

    // ---- epilogue: O / l, coalesced fp32 writes
    float inv[4];
#pragma unroll
    for (int r = 0; r < 4; ++r) {
        const float lr = __shfl(lrun, (L & 48) + ((L & 48) >> 2) + r);
        inv[r] = 1.0f / lr;
    }
    float* op = og + (size_t)b * SEQ * DIM;
#pragma unroll
    for (int r = 0; r < 4; ++r) {
        const int row = qbase + w * 16 + quad * 4 + r;
#pragma unroll
        for (int nb = 0; nb < 4; ++nb)
            op[(size_t)row * DIM + nb * 16 + c15] = Oacc[nb][r] * inv[r];
    }
}

extern "C" void kernel_launch(void* const* d_in, const int* in_sizes, int n_in,
                              void* d_out, int out_size, void* d_ws, size_t ws_size,
                              hipStream_t stream) {
    (void)in_sizes; (void)n_in; (void)out_size;
    const float* q = (const float*)d_in[0];
    const float* k = (const float*)d_in[1];
    const float* v = (const float*)d_in[2];
    const int*   m = (const int*)d_in[3];
    float* o = (float*)d_out;
    const size_t need = (size_t)BATCH * NKT * 4096 * sizeof(short) * 2; // 8 MB
    dim3 grid(SEQ / QT, BATCH);
    if (ws_size >= need) {
        short* kw = (short*)d_ws;
        short* vw = kw + (size_t)BATCH * NKT * 4096;
        prep_kv<<<dim3(BATCH * NKT), 256, 0, stream>>>(k, v, kw, vw);
        attn_fwd<true><<<grid, 256, 0, stream>>>(q, k, v, m, o, kw, vw);
    } else {
        attn_fwd<false><<<grid, 256, 0, stream>>>(q, k, v, m, o, nullptr, nullptr);
    }
}

// Round 5
// 131.483 us; speedup vs baseline: 1.6188x; 1.2640x over previous
//
#include <hip/hip_runtime.h>

// Attention: B=8, N=4096, D=64, fp32 in/out, causal + padding mask.
// R5: no-running-max softmax (fixed M=0, log2 domain, clamp 80) -> zero
//     cross-lane ops in the k-loop; 8 waves/block with key-split (waves
//     0-3 keys 0-31, 4-7 keys 32-63 of the same tile), add-merge at end;
//     balanced 1D grid (b=id&7, qb complementary pairing); mask staged
//     once per block as float addend. Async bf16 staging from d_ws prep.

#define BATCH 8
#define SEQ   4096
#define DIM   64
#define QT    64
#define NKT   (SEQ / 64)

typedef __attribute__((ext_vector_type(8))) short bf16x8;
typedef __attribute__((ext_vector_type(4))) float f32x4;

__device__ inline short f2bf(float f) {
    unsigned u = __builtin_bit_cast(unsigned, f);
    u += 0x7FFFu + ((u >> 16) & 1u);   // RNE
    return (short)(u >> 16);
}

// pack bf16(a) | bf16(b)<<16 (round-half-up bias + byte perm)
__device__ inline unsigned pk2bf(float a, float b) {
    unsigned ua = __builtin_bit_cast(unsigned, a) + 0x8000u;
    unsigned ub = __builtin_bit_cast(unsigned, b) + 0x8000u;
    return __builtin_amdgcn_perm(ub, ua, 0x07060302u);
}

__device__ inline float fast_exp2(float x) {
#if __has_builtin(__builtin_amdgcn_exp2f)
    return __builtin_amdgcn_exp2f(x);
#else
    return exp2f(x);
#endif
}

__device__ inline void gl_lds16(const void* g, void* l) {
    __builtin_amdgcn_global_load_lds(
        (const __attribute__((address_space(1))) void*)g,
        (__attribute__((address_space(3))) void*)l, 16, 0, 0);
}

// ---- pre-pass: fp32 K,V -> bf16 tiles, LDS-ready layouts ----
// K tile: cell(dchunk 0..7, key 0..63) = dchunk*64+key, 8 shorts (d in chunk)
// V tile: cell(kchunk 0..7, d 0..63)  = kchunk*64+d,   8 shorts (key in chunk)
__global__ __launch_bounds__(256)
void prep_kv(const float* __restrict__ kg, const float* __restrict__ vg,
             short* __restrict__ kw, short* __restrict__ vw) {
    const int tile = blockIdx.x;            // b*NKT + kt
    const float* kp = kg + (size_t)tile * 64 * DIM;
    const float* vp = vg + (size_t)tile * 64 * DIM;
    short* ko = kw + (size_t)tile * 4096;
    short* vo = vw + (size_t)tile * 4096;
    const int t = threadIdx.x;
#pragma unroll
    for (int i = 0; i < 4; ++i) {
        const int flat = i * 256 + t;
        const int key = flat >> 4, d0 = (flat & 15) * 4;
        const float4 kv = *(const float4*)(kp + (size_t)key * DIM + d0);
        uint2 kpk;
        kpk.x = pk2bf(kv.x, kv.y); kpk.y = pk2bf(kv.z, kv.w);
        *(uint2*)(ko + (((d0 >> 3) << 6) + key) * 8 + (d0 & 7)) = kpk;
        const float4 vv = *(const float4*)(vp + (size_t)key * DIM + d0);
        const int kc = key >> 3, jk = key & 7;
        vo[((kc << 6) + d0 + 0) * 8 + jk] = f2bf(vv.x);
        vo[((kc << 6) + d0 + 1) * 8 + jk] = f2bf(vv.y);
        vo[((kc << 6) + d0 + 2) * 8 + jk] = f2bf(vv.z);
        vo[((kc << 6) + d0 + 3) * 8 + jk] = f2bf(vv.w);
    }
}

template <bool WS>
__global__ __launch_bounds__(512, 4)
void attn_fwd(const float* __restrict__ qg, const float* __restrict__ kg,
              const float* __restrict__ vg, const int* __restrict__ mg,
              float* __restrict__ og, const short* __restrict__ kw,
              const short* __restrict__ vw) {
    // LDS: Kb[2][4096]sh | Vb[2][4096]sh | Pb[8][16*40]sh | Ml[4096]f
    __shared__ __align__(16) char smem[59392];
    short* KbS = (short*)smem;                 // 16384 B
    short* VbS = (short*)(smem + 16384);       // 16384 B
    short* PbS = (short*)(smem + 32768);       // 10240 B
    float* Ml  = (float*)(smem + 43008);       // 16384 B
    // epilogue merge region aliases Kb/Vb (after final barrier)
    float* OX = (float*)smem;                  // [4][16][64] f32 = 16 KB
    float* LB = (float*)(smem + 16384);        // [4][16]

    const int t    = threadIdx.x;
    const int w    = t >> 6;        // wave 0..7
    const int L    = t & 63;
    const int c15  = L & 15;
    const int quad = L >> 4;
    const int qsub = w & 3;         // q sub-tile (16 rows)
    const int kh   = w >> 2;        // key half: 0 -> keys 0..31, 1 -> 32..63

    // balanced 1D mapping: b = id&7 (XCD-batch locality), qb pairing j <-> 63-j
    const int id = blockIdx.x;
    const int b  = id & 7;
    const int j  = id >> 3;
    const int qb = (j < 32) ? (63 - j) : (j - 32);
    const int qbase  = qb * QT;
    const int ntiles = qb + 1;

    const float* qp = qg + (size_t)b * SEQ * DIM;
    const float* kp = kg + (size_t)b * SEQ * DIM;
    const float* vp = vg + (size_t)b * SEQ * DIM;
    const int*   mp = mg + (size_t)b * SEQ;
    const short* kwb = WS ? kw + (size_t)b * NKT * 4096 : nullptr;
    const short* vwb = WS ? vw + (size_t)b * NKT * 4096 : nullptr;

    const int qrow = qbase + qsub * 16 + c15;   // lane's q column (S^T)
    const float qscale = 0.125f * 1.44269504088896340736f; // 1/sqrt(64)*log2e

    // Q B-fragments, scale folded. n=lane&15(=q), k=quad*8+j (+32c)
    bf16x8 Qf[2];
#pragma unroll
    for (int c = 0; c < 2; ++c) {
        const float* src = qp + (size_t)qrow * DIM + c * 32 + quad * 8;
        float4 x = *(const float4*)(src);
        float4 y = *(const float4*)(src + 4);
        bf16x8 f;
        f[0] = f2bf(x.x * qscale); f[1] = f2bf(x.y * qscale);
        f[2] = f2bf(x.z * qscale); f[3] = f2bf(x.w * qscale);
        f[4] = f2bf(y.x * qscale); f[5] = f2bf(y.y * qscale);
        f[6] = f2bf(y.z * qscale); f[7] = f2bf(y.w * qscale);
        Qf[c] = f;
    }

    // async stage tile kt into buffer bs: wave w covers shorts [w*512, w*512+512)
    auto stage = [&](int bs, int kt) {
        const short* ks = kwb + (size_t)kt * 4096;
        const short* vs = vwb + (size_t)kt * 4096;
        const int off = w << 9;                  // wave-uniform
        gl_lds16(ks + off + (L << 3), KbS + bs * 4096 + off);
        gl_lds16(vs + off + (L << 3), VbS + bs * 4096 + off);
    };

    // mask -> float addend, once per block (only the tiles we'll touch)
    for (int i = t; i < ntiles * 64; i += 512)
        Ml[i] = mp[i] ? 0.0f : -1e30f;

    float lsum = 0.0f;
    f32x4 Oacc[4];
#pragma unroll
    for (int nb = 0; nb < 4; ++nb) Oacc[nb] = (f32x4){0.f, 0.f, 0.f, 0.f};

    if constexpr (WS) stage(0, 0);

    short* Pw = PbS + w * 640;   // [q 0..15][klocal 0..31], row stride 40

    for (int kt = 0; kt < ntiles; ++kt) {
        const int cur = WS ? (kt & 1) : 0;

        if constexpr (!WS) {
            __syncthreads();   // previous reads done
#pragma unroll
            for (int it = 0; it < 2; ++it) {
                const int flat = it * 512 + t;        // 0..1023
                const int key = flat >> 4, d0 = (flat & 15) * 4;
                const float4 kv = *(const float4*)(kp + (size_t)(kt * 64 + key) * DIM + d0);
                uint2 kk;
                kk.x = pk2bf(kv.x, kv.y); kk.y = pk2bf(kv.z, kv.w);
                *(uint2*)&KbS[(((d0 >> 3) << 6) + key) * 8 + (d0 & 7)] = kk;
                const float4 vv = *(const float4*)(vp + (size_t)(kt * 64 + key) * DIM + d0);
                const int kc = key >> 3, jk = key & 7;
                VbS[((kc << 6) + d0 + 0) * 8 + jk] = f2bf(vv.x);
                VbS[((kc << 6) + d0 + 1) * 8 + jk] = f2bf(vv.y);
                VbS[((kc << 6) + d0 + 2) * 8 + jk] = f2bf(vv.z);
                VbS[((kc << 6) + d0 + 3) * 8 + jk] = f2bf(vv.w);
            }
            __syncthreads();
        } else {
            __syncthreads();   // drains stage(kt); prev reads of buf cur^1 done
            if (kt + 1 < ntiles) stage(cur ^ 1, kt + 1);
        }

        const short* Kt = KbS + cur * 4096;
        const short* Vt = VbS + cur * 4096;

        // ---- S^T = K @ Q^T for this wave's 2 key-blocks (kb = 2*kh + i)
        f32x4 sacc[2];
        sacc[0] = (f32x4){0.f, 0.f, 0.f, 0.f};
        sacc[1] = (f32x4){0.f, 0.f, 0.f, 0.f};
#pragma unroll
        for (int c = 0; c < 2; ++c) {
#pragma unroll
            for (int i = 0; i < 2; ++i) {
                bf16x8 kf = *(const bf16x8*)&Kt[(((quad + 4 * c) << 6) + (2 * kh + i) * 16 + c15) * 8];
                sacc[i] = __builtin_amdgcn_mfma_f32_16x16x32_bf16(kf, Qf[c], sacc[i], 0, 0, 0);
            }
        }

        // ---- mask + exp2 (no running max; clamp for safety), P pack
        const bool diag = (kt == ntiles - 1);
#pragma unroll
        for (int i = 0; i < 2; ++i) {
            const int kb = 2 * kh + i;
            const float4 ma = *(const float4*)&Ml[kt * 64 + kb * 16 + quad * 4];
            const float mar[4] = {ma.x, ma.y, ma.z, ma.w};
            float p[4];
#pragma unroll
            for (int r = 0; r < 4; ++r) {
                float s = sacc[i][r] + mar[r];
                if (diag) {
                    const int keyg = kt * 64 + kb * 16 + quad * 4 + r;
                    if (keyg > qrow) s = -1e30f;
                }
                p[r] = fast_exp2(fminf(s, 80.0f));
                lsum += p[r];
            }
            uint2 pp;
            pp.x = pk2bf(p[0], p[1]);
            pp.y = pk2bf(p[2], p[3]);
            *(uint2*)&Pw[c15 * 40 + i * 16 + quad * 4] = pp;
        }

        // ---- O += P @ V over this wave's 32 keys (one MFMA per nb)
        bf16x8 pf = *(const bf16x8*)&Pw[c15 * 40 + quad * 8];
#pragma unroll
        for (int nb = 0; nb < 4; ++nb) {
            bf16x8 vf = *(const bf16x8*)&Vt[(((kh * 4 + quad) << 6) + nb * 16 + c15) * 8];
            Oacc[nb] = __builtin_amdgcn_mfma_f32_16x16x32_bf16(pf, vf, Oacc[nb], 0, 0, 0);
        }
    }

    // ---- epilogue: reduce l across quads, merge key-halves, write out
    lsum += __shfl_xor(lsum, 16);
    lsum += __shfl_xor(lsum, 32);      // lane now has l_half(q=c15)

    __syncthreads();                    // all K/V reads done; safe to alias
    if (w >= 4) {
        const int g = w & 3;
#pragma unroll
        for (int r = 0; r < 4; ++r) {
            const int q = quad * 4 + r;
#pragma unroll
            for (int nb = 0; nb < 4; ++nb)
                OX[(g * 16 + q) * 64 + nb * 16 + c15] = Oacc[nb][r];
        }
        if (quad == 0) LB[g * 16 + c15] = lsum;
    }
    __syncthreads();
    if (w < 4) {
        const float inv = 1.0f / (lsum + LB[w * 16 + c15]);
        float* op = og + (size_t)b * SEQ * DIM;
#pragma unroll
        for (int r = 0; r < 4; ++r) {
            const float ir = __shfl(inv, (L & 48) + ((L & 48) >> 2) + r);
            const int row = qbase + w * 16 + quad * 4 + r;
#pragma unroll
            for (int nb = 0; nb < 4; ++nb)
                op[(size_t)row * DIM + nb * 16 + c15] =
                    (Oacc[nb][r] + OX[(w * 16 + quad * 4 + r) * 64 + nb * 16 + c15]) * ir;
        }
    }
}

extern "C" void kernel_launch(void* const* d_in, const int* in_sizes, int n_in,
                              void* d_out, int out_size, void* d_ws, size_t ws_size,
                              hipStream_t stream) {
    (void)in_sizes; (void)n_in; (void)out_size;
    const float* q = (const float*)d_in[0];
    const float* k = (const float*)d_in[1];
    const float* v = (const float*)d_in[2];
    const int*   m = (const int*)d_in[3];
    float* o = (float*)d_out;
    const size_t need = (size_t)BATCH * NKT * 4096 * sizeof(short) * 2; // 8 MB
    if (ws_size >= need) {
        short* kw = (short*)d_ws;
        short* vw = kw + (size_t)BATCH * NKT * 4096;
        prep_kv<<<dim3(BATCH * NKT), 256, 0, stream>>>(k, v, kw, vw);
        attn_fwd<true><<<dim3(512), 512, 0, stream>>>(q, k, v, m, o, kw, vw);
    } else {
        attn_fwd<false><<<dim3(512), 512, 0, stream>>>(q, k, v, m, o, nullptr, nullptr);
    }
}